// Round 2
// baseline (370.647 us; speedup 1.0000x reference)
//
#include <hip/hip_runtime.h>
#include <math.h>

static constexpr int T_TOK = 16384;   // 4*4096 tokens
static constexpr int E     = 256;     // experts
static constexpr int H     = 2048;    // hidden dim

// ---------------------------------------------------------------------------
// Kernel 1: logits[t][e] = sum_k X[t][k] * W[e][k]
// 128x64 tile, BK=16, 256 threads, 8x4 micro-tile.
// fp32 FMA within each BK=16 slab, fp64 accumulation across slabs:
// per-logit error ~1e-7 (vs ~1.4e-6 for plain fp32 chain) at ~fp32 speed.
// ---------------------------------------------------------------------------
__global__ __launch_bounds__(256) void gemm_logits(const float* __restrict__ X,
                                                   const float* __restrict__ W,
                                                   float* __restrict__ C) {
    __shared__ float As[16][128];
    __shared__ float Bs[16][64];

    const int bn = blockIdx.x;          // 0..3   (expert col block, 64 wide)
    const int bm = blockIdx.y;          // 0..127 (token row block, 128 tall)
    const int tid = threadIdx.x;
    const int tx = tid & 15, ty = tid >> 4;

    // staging A: each thread loads 8 contiguous floats of one row (2 float4)
    const int ar = tid >> 1;            // 0..127
    const int ah = (tid & 1) * 8;       // 0 or 8
    // staging B: each thread loads 4 contiguous floats of one row (1 float4)
    const int br = tid >> 2;            // 0..63
    const int bo = (tid & 3) * 4;       // 0,4,8,12

    const float* Xp = X + (size_t)(bm * 128 + ar) * H + ah;
    const float* Wp = W + (size_t)(bn * 64 + br) * H + bo;

    float4 a0 = *(const float4*)(Xp);
    float4 a1 = *(const float4*)(Xp + 4);
    float4 b0 = *(const float4*)(Wp);

    double acc[8][4];
#pragma unroll
    for (int i = 0; i < 8; ++i)
#pragma unroll
        for (int j = 0; j < 4; ++j) acc[i][j] = 0.0;

    const int NK = H / 16;
    for (int kt = 0; kt < NK; ++kt) {
        __syncthreads();
        As[ah + 0][ar] = a0.x; As[ah + 1][ar] = a0.y;
        As[ah + 2][ar] = a0.z; As[ah + 3][ar] = a0.w;
        As[ah + 4][ar] = a1.x; As[ah + 5][ar] = a1.y;
        As[ah + 6][ar] = a1.z; As[ah + 7][ar] = a1.w;
        Bs[bo + 0][br] = b0.x; Bs[bo + 1][br] = b0.y;
        Bs[bo + 2][br] = b0.z; Bs[bo + 3][br] = b0.w;
        __syncthreads();

        if (kt + 1 < NK) {
            const float* xn = Xp + (kt + 1) * 16;
            const float* wn = Wp + (kt + 1) * 16;
            a0 = *(const float4*)(xn);
            a1 = *(const float4*)(xn + 4);
            b0 = *(const float4*)(wn);
        }

        float p[8][4];
#pragma unroll
        for (int i = 0; i < 8; ++i)
#pragma unroll
            for (int j = 0; j < 4; ++j) p[i][j] = 0.f;

#pragma unroll
        for (int kk = 0; kk < 16; ++kk) {
            float4 xa0 = *(const float4*)&As[kk][ty * 4];
            float4 xa1 = *(const float4*)&As[kk][64 + ty * 4];
            float4 yb0 = *(const float4*)&Bs[kk][tx * 4];
            float xa[8] = {xa0.x, xa0.y, xa0.z, xa0.w, xa1.x, xa1.y, xa1.z, xa1.w};
            float yb[4] = {yb0.x, yb0.y, yb0.z, yb0.w};
#pragma unroll
            for (int i = 0; i < 8; ++i)
#pragma unroll
                for (int j = 0; j < 4; ++j)
                    p[i][j] = fmaf(xa[i], yb[j], p[i][j]);
        }

#pragma unroll
        for (int i = 0; i < 8; ++i)
#pragma unroll
            for (int j = 0; j < 4; ++j) acc[i][j] += (double)p[i][j];
    }

    const int row0 = bm * 128;
    const int col0 = bn * 64 + tx * 4;
#pragma unroll
    for (int i = 0; i < 8; ++i) {
        int m = row0 + ((i < 4) ? (ty * 4 + i) : (64 + ty * 4 + (i - 4)));
        float4 v = make_float4((float)acc[i][0], (float)acc[i][1],
                               (float)acc[i][2], (float)acc[i][3]);
        *(float4*)&C[(size_t)m * E + col0] = v;
    }
}

// ---------------------------------------------------------------------------
// Kernel 2: routing. 64 threads/block, one token per thread, biased scores
// staged once in LDS. Double-precision sigmoid rounded to f32 (correctly
// rounded), then f32 comparisons matching numpy's pipeline bitwise whenever
// the f32 scores agree.
// ---------------------------------------------------------------------------
__global__ __launch_bounds__(64) void route_kernel(const float* __restrict__ logits,
                                                   const float* __restrict__ bias,
                                                   float* __restrict__ out) {
    __shared__ float sc[64][257];   // biased scores; +1 pad (2-way alias = free)
    const int tid = threadIdx.x;
    const int tok = blockIdx.x * 64 + tid;
    const float* L = logits + (size_t)tok * E;

    // scores_for_choice = f32(correctly-rounded sigmoid) + f32 bias
    for (int e = 0; e < E; ++e) {
        double s = 1.0 / (1.0 + exp(-(double)L[e]));
        sc[tid][e] = (float)s + bias[e];
    }

    // per-group score: sum of top-2 biased scores (f32 compares, f32 add)
    float gs[8];
#pragma unroll
    for (int g = 0; g < 8; ++g) {
        float m1 = -1e30f, m2 = -1e30f;
        for (int i = 0; i < 32; ++i) {
            float s = sc[tid][g * 32 + i];
            if (s > m1)      { m2 = m1; m1 = s; }
            else if (s > m2) { m2 = s; }
        }
        gs[g] = m1 + m2;
    }

    // top-4 groups (value desc, index asc on ties — matches lax.top_k)
    unsigned gmask = 0;
#pragma unroll
    for (int g = 0; g < 8; ++g) {
        int rank = 0;
#pragma unroll
        for (int h = 0; h < 8; ++h) {
            if (h == g) continue;
            if (gs[h] > gs[g] || (gs[h] == gs[g] && h < g)) ++rank;
        }
        if (rank < 4) gmask |= (1u << g);
    }

    // top-8 experts over tmp_scores (masked entries are exactly 0.0, like np)
    int   idx[8];
    float w[8];
    float wsum = 0.f;
#pragma unroll
    for (int p = 0; p < 8; ++p) {
        float best = -1e30f;
        int   bi   = 0;
        for (int e = 0; e < E; ++e) {
            bool allowed = (gmask >> (e >> 5)) & 1u;
            float v = allowed ? sc[tid][e] : 0.0f;   // np's tmp_scores semantics
            if (v > best) { best = v; bi = e; }      // strict > => lowest idx tie
        }
        idx[p] = bi;
        sc[tid][bi] = -1e30f;                        // mark used
        // weight from UNbiased scores: recompute correctly-rounded sigmoid
        double s = 1.0 / (1.0 + exp(-(double)L[bi]));
        float sw = (float)s;
        w[p] = sw;
        wsum += sw;
    }

    const float scale = 2.5f / (wsum + 1e-20f);
    float* oi = out + (size_t)tok * 8;                       // topk_idx (as float)
    float* ow = out + (size_t)T_TOK * 8 + (size_t)tok * 8;   // topk_weight
#pragma unroll
    for (int p = 0; p < 8; ++p) {
        oi[p] = (float)idx[p];
        ow[p] = w[p] * scale;
    }
}

// ---------------------------------------------------------------------------
extern "C" void kernel_launch(void* const* d_in, const int* in_sizes, int n_in,
                              void* d_out, int out_size, void* d_ws, size_t ws_size,
                              hipStream_t stream) {
    const float* X = (const float*)d_in[0];   // [4,4096,2048] fp32
    const float* W = (const float*)d_in[1];   // [256,2048]   fp32
    const float* B = (const float*)d_in[2];   // [256]        fp32
    float* out     = (float*)d_out;           // [T*8 idx][T*8 weight] as fp32
    float* logits  = (float*)d_ws;            // 16384*256*4 = 16 MB scratch

    dim3 gg(E / 64, T_TOK / 128);             // (4, 128) = 512 blocks
    gemm_logits<<<gg, 256, 0, stream>>>(X, W, logits);
    route_kernel<<<T_TOK / 64, 64, 0, stream>>>(logits, B, out);
}

// Round 3
// 281.192 us; speedup vs baseline: 1.3181x; 1.3181x over previous
//
#include <hip/hip_runtime.h>
#include <math.h>

static constexpr int T_TOK = 16384;   // 4*4096 tokens
static constexpr int E     = 256;     // experts
static constexpr int H     = 2048;    // hidden dim

// ---------------------------------------------------------------------------
// Kernel 1: partial logits, split-K.
// Cp[z][t][e] = sum_{k in chunk z} X[t][k] * W[e][k]
// 128x64 tile, BK=16, 256 threads, 8x4 micro-tile.
// fp32 FMA within each BK=16 slab, fp64 accumulation across slabs.
// ---------------------------------------------------------------------------
__global__ __launch_bounds__(256) void gemm_logits(const float* __restrict__ X,
                                                   const float* __restrict__ W,
                                                   float* __restrict__ Cp,
                                                   int klen) {
    __shared__ float As[16][128];
    __shared__ float Bs[16][64];

    const int bn = blockIdx.x;          // 0..3   (expert col block, 64 wide)
    const int bm = blockIdx.y;          // 0..127 (token row block, 128 tall)
    const int kz = blockIdx.z;          // split-K chunk
    const int kbase = kz * klen;
    const int tid = threadIdx.x;
    const int tx = tid & 15, ty = tid >> 4;

    const int ar = tid >> 1;            // 0..127
    const int ah = (tid & 1) * 8;       // 0 or 8
    const int br = tid >> 2;            // 0..63
    const int bo = (tid & 3) * 4;       // 0,4,8,12

    const float* Xp = X + (size_t)(bm * 128 + ar) * H + kbase + ah;
    const float* Wp = W + (size_t)(bn * 64 + br) * H + kbase + bo;

    float4 a0 = *(const float4*)(Xp);
    float4 a1 = *(const float4*)(Xp + 4);
    float4 b0 = *(const float4*)(Wp);

    double acc[8][4];
#pragma unroll
    for (int i = 0; i < 8; ++i)
#pragma unroll
        for (int j = 0; j < 4; ++j) acc[i][j] = 0.0;

    const int NK = klen / 16;
    for (int kt = 0; kt < NK; ++kt) {
        __syncthreads();
        As[ah + 0][ar] = a0.x; As[ah + 1][ar] = a0.y;
        As[ah + 2][ar] = a0.z; As[ah + 3][ar] = a0.w;
        As[ah + 4][ar] = a1.x; As[ah + 5][ar] = a1.y;
        As[ah + 6][ar] = a1.z; As[ah + 7][ar] = a1.w;
        Bs[bo + 0][br] = b0.x; Bs[bo + 1][br] = b0.y;
        Bs[bo + 2][br] = b0.z; Bs[bo + 3][br] = b0.w;
        __syncthreads();

        if (kt + 1 < NK) {
            const float* xn = Xp + (kt + 1) * 16;
            const float* wn = Wp + (kt + 1) * 16;
            a0 = *(const float4*)(xn);
            a1 = *(const float4*)(xn + 4);
            b0 = *(const float4*)(wn);
        }

        float p[8][4];
#pragma unroll
        for (int i = 0; i < 8; ++i)
#pragma unroll
            for (int j = 0; j < 4; ++j) p[i][j] = 0.f;

#pragma unroll
        for (int kk = 0; kk < 16; ++kk) {
            float4 xa0 = *(const float4*)&As[kk][ty * 4];
            float4 xa1 = *(const float4*)&As[kk][64 + ty * 4];
            float4 yb0 = *(const float4*)&Bs[kk][tx * 4];
            float xa[8] = {xa0.x, xa0.y, xa0.z, xa0.w, xa1.x, xa1.y, xa1.z, xa1.w};
            float yb[4] = {yb0.x, yb0.y, yb0.z, yb0.w};
#pragma unroll
            for (int i = 0; i < 8; ++i)
#pragma unroll
                for (int j = 0; j < 4; ++j)
                    p[i][j] = fmaf(xa[i], yb[j], p[i][j]);
        }

#pragma unroll
        for (int i = 0; i < 8; ++i)
#pragma unroll
            for (int j = 0; j < 4; ++j) acc[i][j] += (double)p[i][j];
    }

    float* Cz = Cp + (size_t)kz * T_TOK * E;
    const int row0 = bm * 128;
    const int col0 = bn * 64 + tx * 4;
#pragma unroll
    for (int i = 0; i < 8; ++i) {
        int m = row0 + ((i < 4) ? (ty * 4 + i) : (64 + ty * 4 + (i - 4)));
        float4 v = make_float4((float)acc[i][0], (float)acc[i][1],
                               (float)acc[i][2], (float)acc[i][3]);
        *(float4*)&Cz[(size_t)m * E + col0] = v;
    }
}

// ---------------------------------------------------------------------------
// Kernel 2: fused split-K reduce + routing. 16 lanes per token, 16 experts
// per lane, everything in registers (static indexing only). Correctly-rounded
// double sigmoid; f32 comparisons matching numpy's pipeline; exact lax.top_k
// tie-break (value desc, index asc; masked entries = 0.0).
// ---------------------------------------------------------------------------
__global__ __launch_bounds__(256) void route_kernel(const float* __restrict__ P,
                                                    const float* __restrict__ bias,
                                                    float* __restrict__ out,
                                                    int nsplit) {
    const int sub = threadIdx.x & 15;                    // expert chunk 0..15
    const int tok = blockIdx.x * 16 + (threadIdx.x >> 4);
    const int ebase = sub * 16;

    // ---- fused reduce: logits for my 16 experts (f64 sum of f32 partials)
    double accd[16];
#pragma unroll
    for (int i = 0; i < 16; ++i) accd[i] = 0.0;
    for (int s = 0; s < nsplit; ++s) {
        const float* base = P + (size_t)s * T_TOK * E + (size_t)tok * E + ebase;
#pragma unroll
        for (int v = 0; v < 4; ++v) {
            float4 f = *(const float4*)(base + v * 4);
            accd[v * 4 + 0] += (double)f.x; accd[v * 4 + 1] += (double)f.y;
            accd[v * 4 + 2] += (double)f.z; accd[v * 4 + 3] += (double)f.w;
        }
    }

    // ---- scores (round logit to f32 like np, then correctly-rounded sigmoid)
    float us[16], sc[16];
#pragma unroll
    for (int i = 0; i < 16; ++i) {
        float lg = (float)accd[i];
        double s = 1.0 / (1.0 + exp(-(double)lg));
        us[i] = (float)s;                    // unbiased score (f32)
        sc[i] = us[i] + bias[ebase + i];     // scores_for_choice (f32 add)
    }

    // ---- per-group top-2 sum (group g = sub>>1 spans lanes 2g, 2g+1)
    float m1 = -1e30f, m2 = -1e30f;
#pragma unroll
    for (int i = 0; i < 16; ++i) {
        float s = sc[i];
        if (s > m1)      { m2 = m1; m1 = s; }
        else if (s > m2) { m2 = s; }
    }
    float pm1 = __shfl_xor(m1, 1, 16);
    float pm2 = __shfl_xor(m2, 1, 16);
    float gsum = (m1 >= pm1) ? (m1 + fmaxf(m2, pm1)) : (pm1 + fmaxf(pm2, m1));

    // ---- top-4 groups (value desc, index asc)
    const int g = sub >> 1;
    int rank = 0;
#pragma unroll
    for (int h = 0; h < 8; ++h) {
        float gh = __shfl(gsum, h * 2, 16);
        if (h != g && (gh > gsum || (gh == gsum && h < g))) ++rank;
    }
    const bool sel = (rank < 4);

    // ---- top-8 experts via 8x (local argmax + 16-lane shuffle-argmax)
    unsigned used = 0;
    float myoi = 0.f, myow = 0.f;
    float wsum = 0.f;
#pragma unroll
    for (int p = 0; p < 8; ++p) {
        float bv = -1e30f; int bi = 0x7fff; float bu = 0.f;
#pragma unroll
        for (int i = 0; i < 16; ++i) {
            float v = ((used >> i) & 1u) ? -1e30f : (sel ? sc[i] : 0.0f);
            if (v > bv || (v == bv && (ebase + i) < bi)) {
                bv = v; bi = ebase + i; bu = us[i];
            }
        }
#pragma unroll
        for (int d = 1; d < 16; d <<= 1) {
            float ov = __shfl_xor(bv, d, 16);
            int   oi = __shfl_xor(bi, d, 16);
            float ou = __shfl_xor(bu, d, 16);
            if (ov > bv || (ov == bv && oi < bi)) { bv = ov; bi = oi; bu = ou; }
        }
        if ((bi >> 4) == sub) used |= 1u << (bi & 15);   // owner marks used
        if (sub == p) { myoi = (float)bi; myow = bu; }   // stash p-th result
        wsum += bu;                                      // selection order sum
    }

    const float scale = 2.5f / (wsum + 1e-20f);
    if (sub < 8) {
        out[(size_t)tok * 8 + sub] = myoi;                        // topk_idx
        out[(size_t)T_TOK * 8 + (size_t)tok * 8 + sub] = myow * scale;
    }
}

// ---------------------------------------------------------------------------
extern "C" void kernel_launch(void* const* d_in, const int* in_sizes, int n_in,
                              void* d_out, int out_size, void* d_ws, size_t ws_size,
                              hipStream_t stream) {
    const float* X = (const float*)d_in[0];   // [4,4096,2048] fp32
    const float* W = (const float*)d_in[1];   // [256,2048]   fp32
    const float* B = (const float*)d_in[2];   // [256]        fp32
    float* out     = (float*)d_out;
    float* part    = (float*)d_ws;            // nsplit * 16 MB partials

    const size_t chunkB = (size_t)T_TOK * E * sizeof(float);
    int nsplit = 1;
    if (ws_size >= 4 * chunkB)      nsplit = 4;
    else if (ws_size >= 2 * chunkB) nsplit = 2;
    const int klen = H / nsplit;

    dim3 gg(E / 64, T_TOK / 128, nsplit);     // up to 2048 blocks
    gemm_logits<<<gg, 256, 0, stream>>>(X, W, part, klen);
    route_kernel<<<T_TOK / 16, 256, 0, stream>>>(part, B, out, nsplit);
}